// Round 1
// 377.309 us; speedup vs baseline: 1.1765x; 1.1765x over previous
//
#include <hip/hip_runtime.h>
#include <math.h>

#define N_TOK 16384
#define DM    2048
#define NE    64
#define TOPK  4

#define OFF_TI  0
#define OFF_TS  (N_TOK * TOPK)
#define OFF_SC  (2 * N_TOK * TOPK)
#define OFF_AUX (2 * N_TOK * TOPK + N_TOK * NE)

#define TPB   64              // tokens per block
#define DC    32              // dims per chunk per K-half
#define NCH   (1024 / DC)     // 32 chunks
#define LSTR  68              // u LDS row stride (dwords): 64 dims + 4 pad
#define UBUF  (TPB * LSTR)    // 4352 floats per u buffer
#define UOFF  (2 * UBUF)      // 8704 floats: E region starts here
#define EBUF  (2 * DC * NE)   // 4096 floats per E buffer: [kh][dim][expert]

// Block: 1024 threads = 16 waves, 64 tokens. lane = token.
// wave (eg, kh): experts eg*8..+8, dims kh*1024..+1024 -> acc[8]/lane.
// u: coalesced float4 -> LDS [tok][d] (stride 68), 3-deep prefetch.
// E: was s_load (scalar pipe) -> serialized on sK$ misses + lgkmcnt(0) drains
//    (VALUBusy 12%, 22.8K cyc/chunk). Now: double-buffered LDS staging
//    (vector path, 2-deep prefetch) + uniform-address ds_read_b128 broadcasts.
//    DS-only lgkmcnt is in-order -> compiler counted-waits pipeline deeply.
__global__ __launch_bounds__(1024, 4) void router_main(
    const float* __restrict__ u, const float* __restrict__ E,
    const float* __restrict__ bias, float* __restrict__ out,
    float* __restrict__ ws)
{
  __shared__ float smem[UOFF + 2 * EBUF];   // 67.6 KB; aliased as fin[64][65] after

  const int tid  = threadIdx.x;
  const int lane = tid & 63;
  const int wid  = __builtin_amdgcn_readfirstlane(tid >> 6);
  const int eg   = wid & 7;     // expert group
  const int kh   = wid >> 3;    // K half
  const int tok0 = blockIdx.x * TPB;

  // ---- u staging assignment: thread -> (token, 16B dim-segment) ----
  const int stok  = tid >> 4;        // 0..63
  const int sdseg = tid & 15;        // 0..7 -> kh0 dims, 8..15 -> kh1 dims
  const int skh   = sdseg >> 3;
  const int sdsub = (sdseg & 7) * 4;
  const float* sgbase = u + (size_t)(tok0 + stok) * DM + skh * 1024 + sdsub;
  float* swp = smem + stok * LSTR + sdseg * 4;   // + buf*UBUF

  // ---- E staging assignment: thread -> 16B quad of the [2][DC][NE] chunk ----
  const int eq  = tid & 511;         // quad index within one kh half (512*4 floats)
  const int ekh = tid >> 9;
  const float* egbase = E + (size_t)ekh * 1024 * NE + eq * 4;  // + c*DC*NE
  float* ewp = smem + UOFF + ekh * (DC * NE) + eq * 4;         // + buf*EBUF

  float acc[8];
#pragma unroll
  for (int j = 0; j < 8; ++j) acc[j] = 0.f;

  float4 pf[3];
  pf[0] = *(const float4*)(sgbase + 0 * DC);
  pf[1] = *(const float4*)(sgbase + 1 * DC);
  pf[2] = *(const float4*)(sgbase + 2 * DC);
  float4 epf = *(const float4*)(egbase + 0 * (DC * NE));
  *(float4*)(swp + 0) = pf[0];       // u chunk 0 -> buf 0
  *(float4*)(ewp + 0) = epf;         // E chunk 0 -> buf 0
  epf = *(const float4*)(egbase + 1 * (DC * NE));   // E chunk 1 for next store
  __syncthreads();

  for (int c = 0; c < NCH; ++c) {
    // stage chunk c+1 into the other buffers (their readers sync'd last iter)
    if (c + 1 < NCH) {
      *(float4*)(swp + ((c + 1) & 1) * UBUF) = pf[(c + 1) % 3];
      *(float4*)(ewp + ((c + 1) & 1) * EBUF) = epf;
    }
    if (c + 2 < NCH)                 // refill E prefetch (L2-hot, 1 chunk cover)
      epf = *(const float4*)(egbase + (c + 2) * (DC * NE));
    if (c + 3 < NCH)                 // refill u prefetch slot (HBM, 3 chunks cover)
      pf[c % 3] = *(const float4*)(sgbase + (c + 3) * DC);

    // ---- compute chunk c ----
    const float* sb = smem + (c & 1) * UBUF + lane * LSTR + kh * DC;
    const float* eb = smem + UOFF + (c & 1) * EBUF + kh * (DC * NE) + eg * 8;
#pragma unroll
    for (int s = 0; s < 8; ++s) {         // 4 dims per sub-step
      float4 uf = *(const float4*)(sb + s * 4);   // per-lane ds_read_b128
#pragma unroll
      for (int dd = 0; dd < 4; ++dd) {
        const float* er = eb + (s * 4 + dd) * NE;
        float4 e0 = *(const float4*)(er);         // uniform-addr broadcast b128
        float4 e1 = *(const float4*)(er + 4);
        const float uv = (&uf.x)[dd];
        acc[0] = fmaf(e0.x, uv, acc[0]);
        acc[1] = fmaf(e0.y, uv, acc[1]);
        acc[2] = fmaf(e0.z, uv, acc[2]);
        acc[3] = fmaf(e0.w, uv, acc[3]);
        acc[4] = fmaf(e1.x, uv, acc[4]);
        acc[5] = fmaf(e1.y, uv, acc[5]);
        acc[6] = fmaf(e1.z, uv, acc[6]);
        acc[7] = fmaf(e1.w, uv, acc[7]);
      }
    }
    __syncthreads();
  }

  // ---- cross-wave K-half reduction into fin[64 tok][65] (aliases smem) ----
  float* fin = smem;
  if (kh == 0) {
#pragma unroll
    for (int j = 0; j < 8; ++j) fin[lane * 65 + eg * 8 + j] = acc[j];
  }
  __syncthreads();
  if (kh == 1) {
#pragma unroll
    for (int j = 0; j < 8; ++j) fin[lane * 65 + eg * 8 + j] += acc[j];
  }
  __syncthreads();

  // ---- epilogue: wave w -> tokens w*4..+3, lane = expert ----
  const float be = bias[lane];
  float asum = 0.f;
#pragma unroll
  for (int tt = 0; tt < 4; ++tt) {
    const int t = wid * 4 + tt;
    float x = fin[t * 65 + lane] + be;

    float m = x;
#pragma unroll
    for (int off = 32; off > 0; off >>= 1) m = fmaxf(m, __shfl_xor(m, off));
    float p = expf(x - m);
    float s = p;
#pragma unroll
    for (int off = 32; off > 0; off >>= 1) s += __shfl_xor(s, off);
    float sc = p / s;

    out[OFF_SC + (size_t)(tok0 + t) * NE + lane] = sc;
    asum += sc;

    float v = sc;
#pragma unroll
    for (int k = 0; k < TOPK; ++k) {
      float bv = v;
      int   bi = lane;
#pragma unroll
      for (int off = 32; off > 0; off >>= 1) {
        float ov = __shfl_xor(bv, off);
        int   oi = __shfl_xor(bi, off);
        if (ov > bv || (ov == bv && oi < bi)) { bv = ov; bi = oi; }
      }
      if (lane == k) {
        out[OFF_TI + (size_t)(tok0 + t) * TOPK + k] = (float)bi;
        out[OFF_TS + (size_t)(tok0 + t) * TOPK + k] = bv;
      }
      if (lane == bi) v = -INFINITY;
    }
  }
  atomicAdd(&ws[lane], asum);   // per-expert partial for aux loss
}

__global__ void router_aux(const float* __restrict__ ws, float* __restrict__ out)
{
  const int lane = threadIdx.x & 63;
  float m = ws[lane] * (1.0f / N_TOK);
  float v = m * m;
#pragma unroll
  for (int off = 32; off > 0; off >>= 1) v += __shfl_xor(v, off);
  if (lane == 0) out[OFF_AUX] = v * (float)NE;
}

extern "C" void kernel_launch(void* const* d_in, const int* in_sizes, int n_in,
                              void* d_out, int out_size, void* d_ws, size_t ws_size,
                              hipStream_t stream) {
  const float* u    = (const float*)d_in[0];
  const float* E    = (const float*)d_in[1];
  const float* bias = (const float*)d_in[2];
  float* out = (float*)d_out;
  float* ws  = (float*)d_ws;

  hipMemsetAsync(ws, 0, NE * sizeof(float), stream);
  router_main<<<N_TOK / TPB, 1024, 0, stream>>>(u, E, bias, out, ws);
  router_aux<<<1, 64, 0, stream>>>(ws, out);
}